// Round 1
// baseline (503.750 us; speedup 1.0000x reference)
//
#include <hip/hip_runtime.h>
#include <cmath>

#define B_   8
#define CI_  3
#define CM_  21
#define H_   128
#define W_   128
#define K_   32
#define PAD_ 8
#define PW_  144
#define PH_  144
#define NC_  3   // mask channels per block in iter kernel (21 = 7 groups of 3)

typedef float f4 __attribute__((ext_vector_type(4)));
// alignment-4 view for unaligned (dword-aligned) float4 loads
typedef f4 __attribute__((aligned(4))) f4u;

// 3x3 neighborhood minus center, row-major: (di,dj)-1 offsets
constexpr int OI[8] = {-1,-1,-1, 0, 0, 1, 1, 1};
constexpr int OJ[8] = {-1, 0, 1,-1, 1,-1, 0, 1};

struct PosSoft { float v[K_]; };  // W2 * softmax(pos_aff), host-computed

// ---------------------------------------------------------------------------
// Phase A: per-pixel affinity (softmax over K=32) + constant position term.
// One thread per (b,i,j). Two passes over neighbors (mean/var, then diffs).
// ---------------------------------------------------------------------------
__global__ __launch_bounds__(128) void aff_kernel(const float* __restrict__ imgs,
                                                  float* __restrict__ aff,
                                                  PosSoft ps) {
  const int j = threadIdx.x;     // 0..127
  const int i = blockIdx.x;      // 0..127
  const int b = blockIdx.y;      // 0..7
  const float* img = imgs + (size_t)b * CI_ * H_ * W_;

  float ctr[CI_];
#pragma unroll
  for (int c = 0; c < CI_; ++c) ctr[c] = img[c * H_ * W_ + i * W_ + j];

  float s[CI_] = {0.f, 0.f, 0.f}, s2[CI_] = {0.f, 0.f, 0.f};
#pragma unroll
  for (int k = 0; k < K_; ++k) {
    const int d  = 1 << (k >> 3);
    const int ci = min(max(i + OI[k & 7] * d, 0), H_ - 1);
    const int cj = min(max(j + OJ[k & 7] * d, 0), W_ - 1);
#pragma unroll
    for (int c = 0; c < CI_; ++c) {
      float v = img[c * H_ * W_ + ci * W_ + cj];
      s[c] += v; s2[c] += v * v;
    }
  }

  float inv[CI_];
#pragma unroll
  for (int c = 0; c < CI_; ++c) {
    float mean = s[c] * (1.f / K_);
    float var  = (s2[c] - (float)K_ * mean * mean) * (1.f / (K_ - 1));
    var = fmaxf(var, 0.f);
    inv[c] = 1.f / ((sqrtf(var) + 1e-8f) * 0.3f);   // 1/((std+eps)*W1)
  }

  float araw[K_];
#pragma unroll
  for (int k = 0; k < K_; ++k) {
    const int d  = 1 << (k >> 3);
    const int ci = min(max(i + OI[k & 7] * d, 0), H_ - 1);
    const int cj = min(max(j + OJ[k & 7] * d, 0), W_ - 1);
    float t = 0.f;
#pragma unroll
    for (int c = 0; c < CI_; ++c) {
      float v  = img[c * H_ * W_ + ci * W_ + cj];
      float dd = fabsf(v - ctr[c]) * inv[c];
      t += dd * dd;
    }
    araw[k] = -t * (1.f / CI_);
  }

  // softmax over K
  float m = araw[0];
#pragma unroll
  for (int k = 1; k < K_; ++k) m = fmaxf(m, araw[k]);
  float sum = 0.f;
#pragma unroll
  for (int k = 0; k < K_; ++k) { float e = __expf(araw[k] - m); araw[k] = e; sum += e; }
  const float rs = 1.f / sum;

  float* ap = aff + ((size_t)b * K_) * (H_ * W_) + i * W_ + j;
#pragma unroll
  for (int k = 0; k < K_; ++k) ap[(size_t)k * (H_ * W_)] = araw[k] * rs + ps.v[k];
}

// ---------------------------------------------------------------------------
// Pad masks into edge-replicated 144x144 planes.
// ---------------------------------------------------------------------------
__global__ void pad_kernel(const float* __restrict__ src, float* __restrict__ dst,
                           int total) {
  int idx = blockIdx.x * blockDim.x + threadIdx.x;
  if (idx >= total) return;
  int pj = idx % PW_;
  int t  = idx / PW_;
  int pi = t % PH_;
  int p  = t / PH_;                       // plane = b*CM_+c
  int i = min(max(pi - PAD_, 0), H_ - 1);
  int j = min(max(pj - PAD_, 0), W_ - 1);
  dst[idx] = src[(size_t)p * (H_ * W_) + i * W_ + j];
}

// ---------------------------------------------------------------------------
// Propagation step: out = sum_k aff[k] * src(padded, +offset_k), NC_ channels
// per block. PADOUT=1 -> write padded dst incl. replicated border;
// PADOUT=0 -> write unpadded d_out.
// Block 128 threads: 4 rows x (32 quads of 4 cols).
// ---------------------------------------------------------------------------
template <int PADOUT>
__global__ __launch_bounds__(128) void iter_kernel(const float* __restrict__ src,
                                                   const float* __restrict__ aff,
                                                   float* __restrict__ dst) {
  const int tid = threadIdx.x;
  const int j0  = (tid & 31) * 4;
  const int i   = blockIdx.x * 4 + (tid >> 5);
  const int c0  = blockIdx.y * NC_;
  const int b   = blockIdx.z;

  const float* ap = aff + ((size_t)b * K_) * (H_ * W_) + i * W_ + j0;
  const float* sp = src + ((size_t)(b * CM_ + c0)) * (PH_ * PW_)
                        + (i + PAD_) * PW_ + (j0 + PAD_);

  f4 acc[NC_];
#pragma unroll
  for (int c = 0; c < NC_; ++c) acc[c] = (f4){0.f, 0.f, 0.f, 0.f};

#pragma unroll
  for (int k = 0; k < K_; ++k) {
    const int d    = 1 << (k >> 3);
    const int doff = OI[k & 7] * d * PW_ + OJ[k & 7] * d;
    f4 a = *reinterpret_cast<const f4u*>(ap + (size_t)k * (H_ * W_));
#pragma unroll
    for (int c = 0; c < NC_; ++c) {
      f4 v = *reinterpret_cast<const f4u*>(sp + (size_t)c * (PH_ * PW_) + doff);
      acc[c] += a * v;
    }
  }

  if (PADOUT) {
    // rows to write: main row, plus replicated border rows for i==0 / i==127
    const int r0 = (i == 0)      ? 0        : (i + PAD_);
    const int r1 = (i == H_ - 1) ? (PH_ - 1) : (i + PAD_);
#pragma unroll
    for (int c = 0; c < NC_; ++c) {
      float* dc = dst + ((size_t)(b * CM_ + c0 + c)) * (PH_ * PW_);
      for (int r = r0; r <= r1; ++r) {
        float* row = dc + r * PW_;
        *reinterpret_cast<f4*>(row + PAD_ + j0) = acc[c];   // 16B aligned
        if (j0 == 0) {
          for (int x = 0; x < PAD_; ++x) row[x] = acc[c].x;
        }
        if (j0 == W_ - 4) {
          for (int x = PW_ - PAD_; x < PW_; ++x) row[x] = acc[c].w;
        }
      }
    }
  } else {
    float* dc = dst + ((size_t)(b * CM_ + c0)) * (H_ * W_) + i * W_ + j0;
#pragma unroll
    for (int c = 0; c < NC_; ++c) {
      *reinterpret_cast<f4*>(dc + (size_t)c * (H_ * W_)) = acc[c];
    }
  }
}

// ---------------------------------------------------------------------------
extern "C" void kernel_launch(void* const* d_in, const int* in_sizes, int n_in,
                              void* d_out, int out_size, void* d_ws, size_t ws_size,
                              hipStream_t stream) {
  const float* imgs  = (const float*)d_in[0];
  const float* masks = (const float*)d_in[1];
  float* out = (float*)d_out;

  // workspace layout: aff (16.78 MB) | P0 (13.93 MB) | P1 (13.93 MB)  ~= 44.6 MB
  char* ws = (char*)d_ws;
  const size_t affBytes = (size_t)B_ * K_ * H_ * W_ * sizeof(float);
  const size_t padBytes = (size_t)B_ * CM_ * PH_ * PW_ * sizeof(float);
  float* aff = (float*)ws;
  float* P0  = (float*)(ws + affBytes);
  float* P1  = (float*)(ws + affBytes + padBytes);

  // host-side constant: W2 * softmax(pos_aff) over K=32
  PosSoft ps;
  {
    const double pv[8] = {1.4142135623730951, 1.0, 1.4142135623730951, 1.0,
                          1.0, 1.4142135623730951, 1.0, 1.4142135623730951};
    double pos[K_];
    for (int di = 0; di < 4; ++di) {
      double d = (double)(1 << di);
      for (int o = 0; o < 8; ++o) pos[di * 8 + o] = pv[o] * d;
    }
    double mean = 0; for (int k = 0; k < K_; ++k) mean += pos[k]; mean /= K_;
    double var = 0;  for (int k = 0; k < K_; ++k) { double dd = pos[k] - mean; var += dd * dd; }
    var /= (K_ - 1);
    double sd = sqrt(var);
    double pa[K_]; double m = -1e300;
    for (int k = 0; k < K_; ++k) {
      double r = pos[k] / ((sd + 1e-8) * 0.3);
      pa[k] = -(r * r);
      if (pa[k] > m) m = pa[k];
    }
    double es = 0; for (int k = 0; k < K_; ++k) { pa[k] = exp(pa[k] - m); es += pa[k]; }
    for (int k = 0; k < K_; ++k) ps.v[k] = (float)(0.01 * pa[k] / es);
  }

  aff_kernel<<<dim3(H_, B_), 128, 0, stream>>>(imgs, aff, ps);

  const int total = B_ * CM_ * PH_ * PW_;
  pad_kernel<<<(total + 255) / 256, 256, 0, stream>>>(masks, P0, total);

  dim3 grid(H_ / 4, CM_ / NC_, B_);   // 32 x 7 x 8 = 1792 blocks
  float* s = P0;
  float* d = P1;
  for (int it = 0; it < 9; ++it) {
    iter_kernel<1><<<grid, 128, 0, stream>>>(s, aff, d);
    float* t = s; s = d; d = t;
  }
  iter_kernel<0><<<grid, 128, 0, stream>>>(s, aff, out);
}